// Round 20
// baseline (1582.526 us; speedup 1.0000x reference)
//
#include <hip/hip_runtime.h>

#define TSTEPS 2048
#define NBATCH 512
#define H1 64
#define H2 16

typedef _Float16 h2v __attribute__((ext_vector_type(2)));

__device__ __forceinline__ float fsig(float x) {
    return __builtin_amdgcn_rcpf(1.0f + __builtin_amdgcn_exp2f(-1.4426950408889634f * x));
}
__device__ __forceinline__ float ftanh(float x) {
    // tanh(x) = 1 - 2/(exp2(2x*log2e)+1); saturates correctly at +-inf
    return 1.0f - 2.0f * __builtin_amdgcn_rcpf(1.0f + __builtin_amdgcn_exp2f(2.8853900817779268f * x));
}
// branchless: k2==1 -> sigmoid(x); k2==2 -> tanh(x) = 2*sig(2x)-1
__device__ __forceinline__ float act(float x, float k2) {
    return k2 * fsig(k2 * x) - (k2 - 1.0f);
}

#if __has_builtin(__builtin_amdgcn_fdot2)
__device__ __forceinline__ float dot2(int wp, int hp, float acc) {
    return __builtin_amdgcn_fdot2(__builtin_bit_cast(h2v, wp),
                                  __builtin_bit_cast(h2v, hp), acc, false);
}
#else
__device__ __forceinline__ float dot2(int wp, int hp, float acc) {
    h2v a = __builtin_bit_cast(h2v, wp), b = __builtin_bit_cast(h2v, hp);
    return acc + (float)a.x * (float)b.x + (float)a.y * (float)b.y;
}
#endif

__device__ __forceinline__ int packh2(float a, float b) {
    h2v v; v.x = (_Float16)a; v.y = (_Float16)b;
    return __builtin_bit_cast(int, v);
}
template<int CTRL>
__device__ __forceinline__ float dpp_bcast(float v) {   // quad broadcast
    int r = __builtin_amdgcn_mov_dpp(__float_as_int(v), CTRL, 0xF, 0xF, true);
    return __int_as_float(r);
}

// AGPR write-once / read-in-loop (gfx950 unified file; a-reads are pure VALU)
#define AWRITE(dst, src) asm volatile("v_accvgpr_write_b32 %0, %1" : "=a"(dst) : "v"(src))
#define AREAD(dst, src)  asm volatile("v_accvgpr_read_b32 %0, %1"  : "=v"(dst) : "a"(src))

// ONE WAVE PER BATCH, ZERO BARRIERS — r19 math, weights moved OFF the memory
// pipes. r14(L2)=r15(LDS)=r19(pipelined LDS) all ~1200us because ~100 weight
// dwords/lane/step ran through a CU-SHARED pipe: 2 waves/CU x 33 ds_read_b128
// x ~12cyc = ~800 cyc/step serialized DS occupancy (= the VALUBusy-34% gap).
// Fix: gates g,o + w2 (96 dwords, packed f16) live in AGPRs -- written ONCE
// ("=a"), read per chunk via v_accvgpr_read ("a", volatile so never hoisted):
// 24 VALU reads/chunk (2cyc issue, ~4cyc latency, per-SIMD private, no
// waitcnt) replace 6 ds_read_b128 on the shared pipe. DS drops to h1/h2/ring
// (~11 ops/step). r10's AGPR failure was "+a" pins forcing per-step
// write-backs; write-once/read-only has no such traffic.
__global__ void __launch_bounds__(64, 1)
__attribute__((amdgpu_waves_per_eu(1, 1)))
lstm2_fused(const float* __restrict__ x,      // [512, 2048, 1]
            const float* __restrict__ w_ih1,  // [256, 1]
            const float* __restrict__ w_hh1,  // [256, 64]
            const float* __restrict__ b_ih1,  // [256]
            const float* __restrict__ b_hh1,  // [256]
            const float* __restrict__ w_ih2,  // [64, 64]
            const float* __restrict__ w_hh2,  // [64, 16]
            const float* __restrict__ b_ih2,  // [64]
            const float* __restrict__ b_hh2,  // [64]
            float* __restrict__ out)          // [512, 2048, 16]
{
    const int lane = threadIdx.x;     // 64 threads = 1 wave
    const int b    = blockIdx.x;      // 1 batch per block

    __shared__ float    x_lds[TSTEPS];     // 8 KB
    __shared__ _Float16 h1_lds[H1];        // 128 B
    __shared__ _Float16 h2_lds[H2];        // 32 B
    __shared__ float    ring[32][H2];      // 2 KB output ring

    // ---- stage x[b,:] ----
    {
        const float4* xs = (const float4*)(x + (size_t)b * TSTEPS);
        float4* xd = (float4*)x_lds;
        #pragma unroll
        for (int i = 0; i < 8; ++i) xd[lane + 64 * i] = xs[lane + 64 * i];
    }
    if (lane < 32) ((int*)h1_lds)[lane] = 0;
    if (lane < 8)  ((int*)h2_lds)[lane] = 0;

    // ---- register-resident L1 weights: gates i, f ----
    int w1i[32], w1f[32];
    {
        const float* wri = w_hh1 + (size_t)lane * H1;
        const float* wrf = w_hh1 + (size_t)(H1 + lane) * H1;
        #pragma unroll
        for (int k = 0; k < 32; ++k) {
            w1i[k] = packh2(wri[2 * k], wri[2 * k + 1]);
            w1f[k] = packh2(wrf[2 * k], wrf[2 * k + 1]);
        }
    }

    // ---- AGPR-resident weights: gate g, gate o, w2 (96 dwords/lane) ----
    const int m  = lane >> 2;
    const int g2 = lane & 3;
    const int r2 = g2 * H2 + m;
    int ag_g[32], ag_o[32], ag_u[32];
    {
        const float* wrg = w_hh1 + (size_t)(2 * H1 + lane) * H1;
        const float* wro = w_hh1 + (size_t)(3 * H1 + lane) * H1;
        const float* wr2 = w_ih2 + (size_t)r2 * H1;
        #pragma unroll
        for (int k = 0; k < 32; ++k) {
            int vg = packh2(wrg[2 * k], wrg[2 * k + 1]);
            int vo = packh2(wro[2 * k], wro[2 * k + 1]);
            int vu = packh2(wr2[2 * k], wr2[2 * k + 1]);
            AWRITE(ag_g[k], vg);
            AWRITE(ag_o[k], vo);
            AWRITE(ag_u[k], vu);
        }
    }
    // ---- wh2 resident in VGPRs (8 dwords) ----
    int wh2r[8];
    {
        const float* wrh = w_hh2 + (size_t)r2 * H2;
        #pragma unroll
        for (int k = 0; k < 8; ++k) wh2r[k] = packh2(wrh[2 * k], wrh[2 * k + 1]);
    }

    // ---- per-gate scalars ----
    const float wxi = w_ih1[lane],        wxf = w_ih1[H1 + lane];
    const float wxg = w_ih1[2*H1 + lane], wxo = w_ih1[3*H1 + lane];
    const float bsi = b_ih1[lane] + b_hh1[lane];
    const float bsf = b_ih1[H1+lane] + b_hh1[H1+lane];
    const float bsg = b_ih1[2*H1+lane] + b_hh1[2*H1+lane];
    const float bso = b_ih1[3*H1+lane] + b_hh1[3*H1+lane];
    const float bs2 = b_ih2[r2] + b_hh2[r2];
    const float k22 = (g2 == 2) ? 2.0f : 1.0f;

    float c1 = 0.0f;
    float c2 = 0.0f;
    float* outb = out + (size_t)b * TSTEPS * H2;

    const int4* hs4 = (const int4*)h1_lds;
    int4 hA = make_int4(0, 0, 0, 0), hB = make_int4(0, 0, 0, 0);  // h1(-1) = 0

    for (int p = 0; p <= TSTEPS; ++p) {
        // ---- pre-read h2(p-2) early (used in L2 finish, far below) ----
        const int4* h2p = (const int4*)h2_lds;
        int4 u0 = h2p[0], u1 = h2p[1];

        // ---- output flush: every 16 steps, slots written 16-31 steps ago ----
        const int tau_f = p - 1;
        if (tau_f >= 31 && (tau_f & 15) == 15) {
            const int tau0 = (tau_f & ~15) - 16;
            const int tt = tau0 + (lane >> 2), ch0 = (lane & 3) * 4;
            float4 v = *(const float4*)&ring[tt & 31][ch0];
            *(float4*)(outb + (size_t)tt * H2 + ch0) = v;      // 1 KB coalesced
        }

        // ---- gate accumulators ----
        const float xv = x_lds[p & (TSTEPS - 1)];
        float aI = bsi + wxi * xv;
        float aF = bsf + wxf * xv;
        float aG = bsg + wxg * xv;
        float aO = bso + wxo * xv;
        float a0 = bs2, a1 = 0.f, a2a = 0.f, a3 = 0.f;

        // ---- 4 chunks; per chunk: 24 AGPR reads (VALU) + 42 dots ----
        #pragma unroll
        for (int c = 0; c < 4; ++c) {
            int wg[8], wo[8], wu[8];
            #pragma unroll
            for (int j = 0; j < 8; ++j) {
                AREAD(wg[j], ag_g[8*c + j]);
                AREAD(wo[j], ag_o[8*c + j]);
                AREAD(wu[j], ag_u[8*c + j]);
            }
            int4 nA, nB;
            if (c < 3) { nA = hs4[2*c + 2]; nB = hs4[2*c + 3]; }

            aI = dot2(w1i[8*c+0], hA.x, aI); aI = dot2(w1i[8*c+1], hA.y, aI);
            aI = dot2(w1i[8*c+2], hA.z, aI); aI = dot2(w1i[8*c+3], hA.w, aI);
            aI = dot2(w1i[8*c+4], hB.x, aI); aI = dot2(w1i[8*c+5], hB.y, aI);
            aI = dot2(w1i[8*c+6], hB.z, aI); aI = dot2(w1i[8*c+7], hB.w, aI);

            aF = dot2(w1f[8*c+0], hA.x, aF); aF = dot2(w1f[8*c+1], hA.y, aF);
            aF = dot2(w1f[8*c+2], hA.z, aF); aF = dot2(w1f[8*c+3], hA.w, aF);
            aF = dot2(w1f[8*c+4], hB.x, aF); aF = dot2(w1f[8*c+5], hB.y, aF);
            aF = dot2(w1f[8*c+6], hB.z, aF); aF = dot2(w1f[8*c+7], hB.w, aF);

            aG = dot2(wg[0], hA.x, aG); aG = dot2(wg[1], hA.y, aG);
            aG = dot2(wg[2], hA.z, aG); aG = dot2(wg[3], hA.w, aG);
            aG = dot2(wg[4], hB.x, aG); aG = dot2(wg[5], hB.y, aG);
            aG = dot2(wg[6], hB.z, aG); aG = dot2(wg[7], hB.w, aG);

            aO = dot2(wo[0], hA.x, aO); aO = dot2(wo[1], hA.y, aO);
            aO = dot2(wo[2], hA.z, aO); aO = dot2(wo[3], hA.w, aO);
            aO = dot2(wo[4], hB.x, aO); aO = dot2(wo[5], hB.y, aO);
            aO = dot2(wo[6], hB.z, aO); aO = dot2(wo[7], hB.w, aO);

            a0  = dot2(wu[0], hA.x, a0);  a1  = dot2(wu[1], hA.y, a1);
            a2a = dot2(wu[2], hA.z, a2a); a3  = dot2(wu[3], hA.w, a3);
            a0  = dot2(wu[4], hB.x, a0);  a1  = dot2(wu[5], hB.y, a1);
            a2a = dot2(wu[6], hB.z, a2a); a3  = dot2(wu[7], hB.w, a3);

            if (c < 3) { hA = nA; hB = nB; }
        }

        // ===== Layer 1 finish, timestep p =====
        if (p < TSTEPS) {
            float gi = fsig(aI), gf = fsig(aF), gg = ftanh(aG), go = fsig(aO);
            c1 = gf * c1 + gi * gg;
            float h1n = go * ftanh(c1);
            h1_lds[lane] = (_Float16)h1n;       // ds_write_b16; same-wave FIFO
        }
        // prefetch next step's h pair0 now (after the write; DS FIFO order);
        // its latency hides under the L2 finish below
        hA = hs4[0]; hB = hs4[1];

        // ===== Layer 2 finish, timestep p-1 (same wave, no sync) =====
        if (p >= 1) {
            a0  = dot2(wh2r[0], u0.x, a0);  a1  = dot2(wh2r[1], u0.y, a1);
            a2a = dot2(wh2r[2], u0.z, a2a); a3  = dot2(wh2r[3], u0.w, a3);
            a0  = dot2(wh2r[4], u1.x, a0);  a1  = dot2(wh2r[5], u1.y, a1);
            a2a = dot2(wh2r[6], u1.z, a2a); a3  = dot2(wh2r[7], u1.w, a3);
            float av = act((a0 + a1) + (a2a + a3), k22);
            float gi = dpp_bcast<0x00>(av);     // quad holds (i,f,g,o) of channel m
            float gf = dpp_bcast<0x55>(av);
            float gg = dpp_bcast<0xAA>(av);
            float go = dpp_bcast<0xFF>(av);
            c2 = gf * c2 + gi * gg;
            float h2n = go * ftanh(c2);
            if (g2 == 0) {
                h2_lds[m] = (_Float16)h2n;
                ring[(p - 1) & 31][m] = h2n;
            }
        }
    }

    // ---- tail flush: timesteps 2032..2047 (same wave -> FIFO safe) ----
    {
        const int tt = 2032 + (lane >> 2), ch0 = (lane & 3) * 4;
        float4 v = *(const float4*)&ring[tt & 31][ch0];
        *(float4*)(outb + (size_t)tt * H2 + ch0) = v;
    }
}

extern "C" void kernel_launch(void* const* d_in, const int* in_sizes, int n_in,
                              void* d_out, int out_size, void* d_ws, size_t ws_size,
                              hipStream_t stream) {
    const float* x     = (const float*)d_in[0];
    const float* w_ih1 = (const float*)d_in[1];
    const float* w_hh1 = (const float*)d_in[2];
    const float* b_ih1 = (const float*)d_in[3];
    const float* b_hh1 = (const float*)d_in[4];
    const float* w_ih2 = (const float*)d_in[5];
    const float* w_hh2 = (const float*)d_in[6];
    const float* b_ih2 = (const float*)d_in[7];
    const float* b_hh2 = (const float*)d_in[8];
    float* out = (float*)d_out;

    lstm2_fused<<<NBATCH, 64, 0, stream>>>(x, w_ih1, w_hh1, b_ih1, b_hh1,
                                           w_ih2, w_hh2, b_ih2, b_hh2, out);
}

// Round 21
// 1302.122 us; speedup vs baseline: 1.2153x; 1.2153x over previous
//
#include <hip/hip_runtime.h>

#define TSTEPS 2048
#define NBATCH 512
#define H1 64
#define H2 16

typedef _Float16 h2v __attribute__((ext_vector_type(2)));

__device__ __forceinline__ float fsig(float x) {
    return __builtin_amdgcn_rcpf(1.0f + __builtin_amdgcn_exp2f(-1.4426950408889634f * x));
}
__device__ __forceinline__ float ftanh(float x) {
    // tanh(x) = 1 - 2/(exp2(2x*log2e)+1); saturates correctly at +-inf
    return 1.0f - 2.0f * __builtin_amdgcn_rcpf(1.0f + __builtin_amdgcn_exp2f(2.8853900817779268f * x));
}
// branchless: k2==1 -> sigmoid(x); k2==2 -> tanh(x) = 2*sig(2x)-1
__device__ __forceinline__ float act(float x, float k2) {
    return k2 * fsig(k2 * x) - (k2 - 1.0f);
}

#if __has_builtin(__builtin_amdgcn_fdot2)
__device__ __forceinline__ float dot2(int wp, int hp, float acc) {
    return __builtin_amdgcn_fdot2(__builtin_bit_cast(h2v, wp),
                                  __builtin_bit_cast(h2v, hp), acc, false);
}
#else
__device__ __forceinline__ float dot2(int wp, int hp, float acc) {
    h2v a = __builtin_bit_cast(h2v, wp), b = __builtin_bit_cast(h2v, hp);
    return acc + (float)a.x * (float)b.x + (float)a.y * (float)b.y;
}
#endif

__device__ __forceinline__ int packh2(float a, float b) {
    h2v v; v.x = (_Float16)a; v.y = (_Float16)b;
    return __builtin_bit_cast(int, v);
}
template<int CTRL>
__device__ __forceinline__ float dpp_bcast(float v) {   // quad broadcast
    int r = __builtin_amdgcn_mov_dpp(__float_as_int(v), CTRL, 0xF, 0xF, true);
    return __int_as_float(r);
}

#define SBAR() __builtin_amdgcn_sched_barrier(0)

// ONE WAVE PER BATCH, ZERO BARRIERS — r15 math + sched_barrier-pinned
// software pipelining. Evidence r14/r15/r19/r20: ~500cyc issue + ~875cyc
// stall/step, invariant to weight source (L2/LDS/AGPR) -> the stall is
// exposed load latency + recurrence round-trip, and the compiler re-sinks
// every source-level prefetch (r19 ping-pong: VGPR stayed 132). r20 proved
// the allocator CAN grant more (168) when liveness is forced.
// Fix: sched_barrier(0) pins (a) each chunk's 6 weight ds_reads BEFORE the
// previous chunk's dots (>=85cyc slack; next-step chunk0 ~150cyc), and
// (b) all 8 h-pair reads right after the h1 ds_write (same-wave FIFO),
// hiding the recurrence round-trip under the L2 finish + flush.
__global__ void __launch_bounds__(64, 1)
__attribute__((amdgpu_waves_per_eu(1, 1)))
lstm2_fused(const float* __restrict__ x,      // [512, 2048, 1]
            const float* __restrict__ w_ih1,  // [256, 1]
            const float* __restrict__ w_hh1,  // [256, 64]
            const float* __restrict__ b_ih1,  // [256]
            const float* __restrict__ b_hh1,  // [256]
            const float* __restrict__ w_ih2,  // [64, 64]
            const float* __restrict__ w_hh2,  // [64, 16]
            const float* __restrict__ b_ih2,  // [64]
            const float* __restrict__ b_hh2,  // [64]
            float* __restrict__ out)          // [512, 2048, 16]
{
    const int lane = threadIdx.x;     // 64 threads = 1 wave
    const int b    = blockIdx.x;      // 1 batch per block

    __shared__ int4     wlds[26][64];      // 26.6 KB streamed weights
    __shared__ float    x_lds[TSTEPS];     // 8 KB
    __shared__ _Float16 h1_lds[H1];        // 128 B
    __shared__ _Float16 h2_lds[H2];        // 32 B
    __shared__ float    ring[32][H2];      // 2 KB output ring

    // ---- stage x[b,:] ----
    {
        const float4* xs = (const float4*)(x + (size_t)b * TSTEPS);
        float4* xd = (float4*)x_lds;
        #pragma unroll
        for (int i = 0; i < 8; ++i) xd[lane + 64 * i] = xs[lane + 64 * i];
    }
    if (lane < 32) ((int*)h1_lds)[lane] = 0;
    if (lane < 8)  ((int*)h2_lds)[lane] = 0;

    // ---- register-resident L1 weights: gates i, f ----
    int w1i[32], w1f[32];
    {
        const float* wri = w_hh1 + (size_t)lane * H1;
        const float* wrf = w_hh1 + (size_t)(H1 + lane) * H1;
        #pragma unroll
        for (int k = 0; k < 32; ++k) {
            w1i[k] = packh2(wri[2 * k], wri[2 * k + 1]);
            w1f[k] = packh2(wrf[2 * k], wrf[2 * k + 1]);
        }
    }
    // ---- LDS-streamed weights: g rows 0..7, o rows 8..15, w2 rows 16..23,
    //      wh2 rows 24..25 (hoisted to regs). Lane-private columns. ----
    const int m  = lane >> 2;
    const int g2 = lane & 3;
    const int r2 = g2 * H2 + m;
    {
        const float* wrg = w_hh1 + (size_t)(2 * H1 + lane) * H1;
        const float* wro = w_hh1 + (size_t)(3 * H1 + lane) * H1;
        const float* wr2 = w_ih2 + (size_t)r2 * H1;
        #pragma unroll
        for (int tq = 0; tq < 8; ++tq) {
            wlds[tq][lane] = make_int4(
                packh2(wrg[8*tq+0], wrg[8*tq+1]), packh2(wrg[8*tq+2], wrg[8*tq+3]),
                packh2(wrg[8*tq+4], wrg[8*tq+5]), packh2(wrg[8*tq+6], wrg[8*tq+7]));
            wlds[8 + tq][lane] = make_int4(
                packh2(wro[8*tq+0], wro[8*tq+1]), packh2(wro[8*tq+2], wro[8*tq+3]),
                packh2(wro[8*tq+4], wro[8*tq+5]), packh2(wro[8*tq+6], wro[8*tq+7]));
            wlds[16 + tq][lane] = make_int4(
                packh2(wr2[8*tq+0], wr2[8*tq+1]), packh2(wr2[8*tq+2], wr2[8*tq+3]),
                packh2(wr2[8*tq+4], wr2[8*tq+5]), packh2(wr2[8*tq+6], wr2[8*tq+7]));
        }
        const float* wrh = w_hh2 + (size_t)r2 * H2;
        wlds[24][lane] = make_int4(packh2(wrh[0], wrh[1]),  packh2(wrh[2], wrh[3]),
                                   packh2(wrh[4], wrh[5]),  packh2(wrh[6], wrh[7]));
        wlds[25][lane] = make_int4(packh2(wrh[8], wrh[9]),  packh2(wrh[10], wrh[11]),
                                   packh2(wrh[12], wrh[13]), packh2(wrh[14], wrh[15]));
    }

    // ---- per-gate scalars ----
    const float wxi = w_ih1[lane],        wxf = w_ih1[H1 + lane];
    const float wxg = w_ih1[2*H1 + lane], wxo = w_ih1[3*H1 + lane];
    const float bsi = b_ih1[lane] + b_hh1[lane];
    const float bsf = b_ih1[H1+lane] + b_hh1[H1+lane];
    const float bsg = b_ih1[2*H1+lane] + b_hh1[2*H1+lane];
    const float bso = b_ih1[3*H1+lane] + b_hh1[3*H1+lane];
    const float bs2 = b_ih2[r2] + b_hh2[r2];
    const float k22 = (g2 == 2) ? 2.0f : 1.0f;

    float c1 = 0.0f;
    float c2 = 0.0f;
    float* outb = out + (size_t)b * TSTEPS * H2;

    const int4* wl  = &wlds[0][0];       // index row*64 + lane
    const int4* hs4 = (const int4*)h1_lds;

    // hoisted wh2, ping-pong weight buffers, resident h pairs
    int4 vh0r = wl[24 * 64 + lane];
    int4 vh1r = wl[25 * 64 + lane];
    int4 wbA[6], wbB[6];
    wbA[0] = wl[(0)  * 64 + lane];  wbA[1] = wl[(1)  * 64 + lane];
    wbA[2] = wl[(8)  * 64 + lane];  wbA[3] = wl[(9)  * 64 + lane];
    wbA[4] = wl[(16) * 64 + lane];  wbA[5] = wl[(17) * 64 + lane];
    int4 hp[8];
    #pragma unroll
    for (int i = 0; i < 8; ++i) hp[i] = make_int4(0, 0, 0, 0);   // h1(-1)=0

// issue chunk Q's 6 streamed reads into buffer WB
#define ISSUE(WB, Q) do {                                        \
    WB[0] = wl[(2*(Q))      * 64 + lane];                        \
    WB[1] = wl[(2*(Q) + 1)  * 64 + lane];                        \
    WB[2] = wl[(8 + 2*(Q))  * 64 + lane];                        \
    WB[3] = wl[(9 + 2*(Q))  * 64 + lane];                        \
    WB[4] = wl[(16 + 2*(Q)) * 64 + lane];                        \
    WB[5] = wl[(17 + 2*(Q)) * 64 + lane];                        \
} while (0)

// dots for chunk C using buffer WU and resident h pair (HA,HB)
#define DOTS(C, WU, HA, HB) do {                                             \
    ai = dot2(w1i[8*C+0], HA.x, ai); ai = dot2(w1i[8*C+1], HA.y, ai);        \
    ai = dot2(w1i[8*C+2], HA.z, ai); ai = dot2(w1i[8*C+3], HA.w, ai);        \
    ai = dot2(w1i[8*C+4], HB.x, ai); ai = dot2(w1i[8*C+5], HB.y, ai);        \
    ai = dot2(w1i[8*C+6], HB.z, ai); ai = dot2(w1i[8*C+7], HB.w, ai);        \
    af = dot2(w1f[8*C+0], HA.x, af); af = dot2(w1f[8*C+1], HA.y, af);        \
    af = dot2(w1f[8*C+2], HA.z, af); af = dot2(w1f[8*C+3], HA.w, af);        \
    af = dot2(w1f[8*C+4], HB.x, af); af = dot2(w1f[8*C+5], HB.y, af);        \
    af = dot2(w1f[8*C+6], HB.z, af); af = dot2(w1f[8*C+7], HB.w, af);        \
    ag = dot2(WU[0].x, HA.x, ag); ag = dot2(WU[0].y, HA.y, ag);              \
    ag = dot2(WU[0].z, HA.z, ag); ag = dot2(WU[0].w, HA.w, ag);              \
    ag = dot2(WU[1].x, HB.x, ag); ag = dot2(WU[1].y, HB.y, ag);              \
    ag = dot2(WU[1].z, HB.z, ag); ag = dot2(WU[1].w, HB.w, ag);              \
    ao = dot2(WU[2].x, HA.x, ao); ao = dot2(WU[2].y, HA.y, ao);              \
    ao = dot2(WU[2].z, HA.z, ao); ao = dot2(WU[2].w, HA.w, ao);              \
    ao = dot2(WU[3].x, HB.x, ao); ao = dot2(WU[3].y, HB.y, ao);              \
    ao = dot2(WU[3].z, HB.z, ao); ao = dot2(WU[3].w, HB.w, ao);              \
    a0  = dot2(WU[4].x, HA.x, a0);  a1  = dot2(WU[4].y, HA.y, a1);           \
    a2a = dot2(WU[4].z, HA.z, a2a); a3  = dot2(WU[4].w, HA.w, a3);           \
    a0  = dot2(WU[5].x, HB.x, a0);  a1  = dot2(WU[5].y, HB.y, a1);           \
    a2a = dot2(WU[5].z, HB.z, a2a); a3  = dot2(WU[5].w, HB.w, a3);           \
} while (0)

    for (int p = 0; p <= TSTEPS; ++p) {
        // ---- pre-read h2(p-2) early (used in L2 finish far below) ----
        const int4* h2p = (const int4*)h2_lds;
        int4 u0 = h2p[0], u1 = h2p[1];

        // ---- output flush: every 16 steps, slots written 16-31 steps ago ----
        const int tau_f = p - 1;
        if (tau_f >= 31 && (tau_f & 15) == 15) {
            const int tau0 = (tau_f & ~15) - 16;
            const int tt = tau0 + (lane >> 2), ch0 = (lane & 3) * 4;
            float4 v = *(const float4*)&ring[tt & 31][ch0];
            *(float4*)(outb + (size_t)tt * H2 + ch0) = v;      // 1 KB coalesced
        }

        // ---- gate accumulators ----
        const float xv = x_lds[p & (TSTEPS - 1)];
        float ai = bsi + wxi * xv;
        float af = bsf + wxf * xv;
        float ag = bsg + wxg * xv;
        float ao = bso + wxo * xv;
        float a0 = bs2, a1 = 0.f, a2a = 0.f, a3 = 0.f;

        // ---- 4 chunks; ISSUE(c+1) pinned BEFORE DOTS(c) by sched_barrier ----
        ISSUE(wbB, 1);
        SBAR();
        DOTS(0, wbA, hp[0], hp[1]);
        ISSUE(wbA, 2);
        SBAR();
        DOTS(1, wbB, hp[2], hp[3]);
        ISSUE(wbB, 3);
        SBAR();
        DOTS(2, wbA, hp[4], hp[5]);
        ISSUE(wbA, 0);                  // next step's chunk 0
        SBAR();
        DOTS(3, wbB, hp[6], hp[7]);

        // ===== Layer 1 finish, timestep p =====
        if (p < TSTEPS) {
            float gi = fsig(ai), gf = fsig(af), gg = ftanh(ag), go = fsig(ao);
            c1 = gf * c1 + gi * gg;
            float h1n = go * ftanh(c1);
            h1_lds[lane] = (_Float16)h1n;       // ds_write_b16; same-wave FIFO
        }
        // refill ALL h pairs now (FIFO sees the new h1); pinned so the reads
        // issue here and their latency hides under the L2 finish below
        hp[0] = hs4[0]; hp[1] = hs4[1]; hp[2] = hs4[2]; hp[3] = hs4[3];
        hp[4] = hs4[4]; hp[5] = hs4[5]; hp[6] = hs4[6]; hp[7] = hs4[7];
        SBAR();

        // ===== Layer 2 finish, timestep p-1 (same wave, no sync) =====
        if (p >= 1) {
            a0  = dot2(vh0r.x, u0.x, a0);  a1  = dot2(vh0r.y, u0.y, a1);
            a2a = dot2(vh0r.z, u0.z, a2a); a3  = dot2(vh0r.w, u0.w, a3);
            a0  = dot2(vh1r.x, u1.x, a0);  a1  = dot2(vh1r.y, u1.y, a1);
            a2a = dot2(vh1r.z, u1.z, a2a); a3  = dot2(vh1r.w, u1.w, a3);
            float av = act((a0 + a1) + (a2a + a3), k22);
            float gi = dpp_bcast<0x00>(av);     // quad holds (i,f,g,o) of channel m
            float gf = dpp_bcast<0x55>(av);
            float gg = dpp_bcast<0xAA>(av);
            float go = dpp_bcast<0xFF>(av);
            c2 = gf * c2 + gi * gg;
            float h2n = go * ftanh(c2);
            if (g2 == 0) {
                h2_lds[m] = (_Float16)h2n;
                ring[(p - 1) & 31][m] = h2n;
            }
        }
    }
#undef DOTS
#undef ISSUE

    // ---- tail flush: timesteps 2032..2047 (same wave -> FIFO safe) ----
    {
        const int tt = 2032 + (lane >> 2), ch0 = (lane & 3) * 4;
        float4 v = *(const float4*)&ring[tt & 31][ch0];
        *(float4*)(outb + (size_t)tt * H2 + ch0) = v;
    }
}

extern "C" void kernel_launch(void* const* d_in, const int* in_sizes, int n_in,
                              void* d_out, int out_size, void* d_ws, size_t ws_size,
                              hipStream_t stream) {
    const float* x     = (const float*)d_in[0];
    const float* w_ih1 = (const float*)d_in[1];
    const float* w_hh1 = (const float*)d_in[2];
    const float* b_ih1 = (const float*)d_in[3];
    const float* b_hh1 = (const float*)d_in[4];
    const float* w_ih2 = (const float*)d_in[5];
    const float* w_hh2 = (const float*)d_in[6];
    const float* b_ih2 = (const float*)d_in[7];
    const float* b_hh2 = (const float*)d_in[8];
    float* out = (float*)d_out;

    lstm2_fused<<<NBATCH, 64, 0, stream>>>(x, w_ih1, w_hh1, b_ih1, b_hh1,
                                           w_ih2, w_hh2, b_ih2, b_hh2, out);
}

// Round 22
// 1167.223 us; speedup vs baseline: 1.3558x; 1.1156x over previous
//
#include <hip/hip_runtime.h>

#define TSTEPS 2048
#define NBATCH 512
#define H1 64
#define H2 16

typedef _Float16 h2v __attribute__((ext_vector_type(2)));

__device__ __forceinline__ float fsig(float x) {
    return __builtin_amdgcn_rcpf(1.0f + __builtin_amdgcn_exp2f(-1.4426950408889634f * x));
}
__device__ __forceinline__ float ftanh(float x) {
    // tanh(x) = 1 - 2/(exp2(2x*log2e)+1); saturates correctly at +-inf
    return 1.0f - 2.0f * __builtin_amdgcn_rcpf(1.0f + __builtin_amdgcn_exp2f(2.8853900817779268f * x));
}
// branchless: k2==1 -> sigmoid(x); k2==2 -> tanh(x) = 2*sig(2x)-1
__device__ __forceinline__ float act(float x, float k2) {
    return k2 * fsig(k2 * x) - (k2 - 1.0f);
}

#if __has_builtin(__builtin_amdgcn_fdot2)
__device__ __forceinline__ float dot2(int wp, int hp, float acc) {
    return __builtin_amdgcn_fdot2(__builtin_bit_cast(h2v, wp),
                                  __builtin_bit_cast(h2v, hp), acc, false);
}
#else
__device__ __forceinline__ float dot2(int wp, int hp, float acc) {
    h2v a = __builtin_bit_cast(h2v, wp), b = __builtin_bit_cast(h2v, hp);
    return acc + (float)a.x * (float)b.x + (float)a.y * (float)b.y;
}
#endif

__device__ __forceinline__ int packh2(float a, float b) {
    h2v v; v.x = (_Float16)a; v.y = (_Float16)b;
    return __builtin_bit_cast(int, v);
}
template<int CTRL>
__device__ __forceinline__ float dpp_bcast(float v) {   // quad broadcast
    int r = __builtin_amdgcn_mov_dpp(__float_as_int(v), CTRL, 0xF, 0xF, true);
    return __int_as_float(r);
}

// FINAL: ONE WAVE PER BATCH, ZERO BARRIERS (r15, best measured: 1173 us).
// 22-round exploration summary:
//  - Barrier-coupled multi-wave designs (r2-r8, r13): 1588-2670 us. Any
//    cross-wave coordination costs >=180 cyc/step on the serial path.
//  - MFMA reformulation (r8): parallelism collapse (32 blocks), 2460 us.
//  - Single-wave variants: weight source L2/LDS/AGPR invariant-or-worse
//    (1175/1173/1582); schedule JIT/ping-pong/sched_barrier invariant-or-
//    worse (1173/1217/1302); SGPR h-broadcast worse (1299); 2-batch-fused
//    worse (2184); producer-consumer worse (1306).
//  - The hipcc backend re-sinks source-level prefetches whenever liveness
//    exceeds ~132 VGPR (r19/r21: explicit pipelining, VGPR stayed 132), so
//    the ~900 cyc/step of exposed latency around the 2048-step serial
//    recurrence cannot be hidden from HIP source at 1 wave/SIMD.
// This kernel is the measured floor: ~470 cyc/step VALU issue + exposed
// recurrence/stream latency; HBM 0.7%, VALUBusy 34%, conflicts ~0.
__global__ void __launch_bounds__(64, 1)
__attribute__((amdgpu_waves_per_eu(1, 1)))
lstm2_fused(const float* __restrict__ x,      // [512, 2048, 1]
            const float* __restrict__ w_ih1,  // [256, 1]
            const float* __restrict__ w_hh1,  // [256, 64]
            const float* __restrict__ b_ih1,  // [256]
            const float* __restrict__ b_hh1,  // [256]
            const float* __restrict__ w_ih2,  // [64, 64]
            const float* __restrict__ w_hh2,  // [64, 16]
            const float* __restrict__ b_ih2,  // [64]
            const float* __restrict__ b_hh2,  // [64]
            float* __restrict__ out)          // [512, 2048, 16]
{
    const int lane = threadIdx.x;     // 64 threads = 1 wave
    const int b    = blockIdx.x;      // 1 batch per block

    __shared__ int4     wlds[26][64];      // 26.6 KB streamed weights
    __shared__ float    x_lds[TSTEPS];     // 8 KB
    __shared__ _Float16 h1_lds[H1];        // 128 B
    __shared__ _Float16 h2_lds[H2];        // 32 B
    __shared__ float    ring[32][H2];      // 2 KB output ring

    // ---- stage x[b,:] ----
    {
        const float4* xs = (const float4*)(x + (size_t)b * TSTEPS);
        float4* xd = (float4*)x_lds;
        #pragma unroll
        for (int i = 0; i < 8; ++i) xd[lane + 64 * i] = xs[lane + 64 * i];
    }
    if (lane < 32) ((int*)h1_lds)[lane] = 0;
    if (lane < 8)  ((int*)h2_lds)[lane] = 0;

    // ---- register-resident L1 weights: gates i (row lane), f (row 64+lane) ----
    int w1i[32], w1f[32];
    {
        const float* wri = w_hh1 + (size_t)lane * H1;
        const float* wrf = w_hh1 + (size_t)(H1 + lane) * H1;
        #pragma unroll
        for (int k = 0; k < 32; ++k) {
            w1i[k] = packh2(wri[2 * k], wri[2 * k + 1]);
            w1f[k] = packh2(wrf[2 * k], wrf[2 * k + 1]);
        }
    }
    // ---- LDS-streamed weights: w1 gate g (tq 0..7), gate o (tq 8..15),
    //      w2 (tq 16..23), wh2 (tq 24..25). Lane-private columns. ----
    const int m  = lane >> 2;
    const int g2 = lane & 3;
    const int r2 = g2 * H2 + m;
    {
        const float* wrg = w_hh1 + (size_t)(2 * H1 + lane) * H1;
        const float* wro = w_hh1 + (size_t)(3 * H1 + lane) * H1;
        const float* wr2 = w_ih2 + (size_t)r2 * H1;
        #pragma unroll
        for (int tq = 0; tq < 8; ++tq) {
            wlds[tq][lane] = make_int4(
                packh2(wrg[8*tq+0], wrg[8*tq+1]), packh2(wrg[8*tq+2], wrg[8*tq+3]),
                packh2(wrg[8*tq+4], wrg[8*tq+5]), packh2(wrg[8*tq+6], wrg[8*tq+7]));
            wlds[8 + tq][lane] = make_int4(
                packh2(wro[8*tq+0], wro[8*tq+1]), packh2(wro[8*tq+2], wro[8*tq+3]),
                packh2(wro[8*tq+4], wro[8*tq+5]), packh2(wro[8*tq+6], wro[8*tq+7]));
            wlds[16 + tq][lane] = make_int4(
                packh2(wr2[8*tq+0], wr2[8*tq+1]), packh2(wr2[8*tq+2], wr2[8*tq+3]),
                packh2(wr2[8*tq+4], wr2[8*tq+5]), packh2(wr2[8*tq+6], wr2[8*tq+7]));
        }
        const float* wrh = w_hh2 + (size_t)r2 * H2;
        wlds[24][lane] = make_int4(packh2(wrh[0], wrh[1]),  packh2(wrh[2], wrh[3]),
                                   packh2(wrh[4], wrh[5]),  packh2(wrh[6], wrh[7]));
        wlds[25][lane] = make_int4(packh2(wrh[8], wrh[9]),  packh2(wrh[10], wrh[11]),
                                   packh2(wrh[12], wrh[13]), packh2(wrh[14], wrh[15]));
    }

    // ---- per-gate scalars ----
    const float wxi = w_ih1[lane],        wxf = w_ih1[H1 + lane];
    const float wxg = w_ih1[2*H1 + lane], wxo = w_ih1[3*H1 + lane];
    const float bsi = b_ih1[lane] + b_hh1[lane];
    const float bsf = b_ih1[H1+lane] + b_hh1[H1+lane];
    const float bsg = b_ih1[2*H1+lane] + b_hh1[2*H1+lane];
    const float bso = b_ih1[3*H1+lane] + b_hh1[3*H1+lane];
    const float bs2 = b_ih2[r2] + b_hh2[r2];
    const float k22 = (g2 == 2) ? 2.0f : 1.0f;

    float c1 = 0.0f;                  // cell of L1 channel `lane`
    float c2 = 0.0f;                  // cell of L2 channel m (replicated per quad)
    float* outb = out + (size_t)b * TSTEPS * H2;

    const int4* wl = &wlds[0][0];     // index tq*64 + lane

    for (int p = 0; p <= TSTEPS; ++p) {
        // ---- output flush: every 16 steps, slots written 16-31 steps ago ----
        const int tau_f = p - 1;
        if (tau_f >= 31 && (tau_f & 15) == 15) {
            const int tau0 = (tau_f & ~15) - 16;
            const int tt = tau0 + (lane >> 2), ch0 = (lane & 3) * 4;
            float4 v = *(const float4*)&ring[tt & 31][ch0];
            *(float4*)(outb + (size_t)tt * H2 + ch0) = v;      // 1 KB coalesced
        }

        // ---- gate accumulators ----
        const float xv = x_lds[p & (TSTEPS - 1)];      // p==TSTEPS value unused
        float ai = bsi + wxi * xv;
        float af = bsf + wxf * xv;
        float ag = bsg + wxg * xv;
        float ao = bso + wxo * xv;
        float a0 = bs2, a1 = 0.f, a2a = 0.f, a3 = 0.f;
        int4 vh0, vh1;                 // wh2, loaded during chunk 2

        // ---- 4 chunks of 8 h-pairs; weights g/o/w2 streamed from LDS ----
        {
            const int4* hs4 = (const int4*)h1_lds;
            #pragma unroll
            for (int c = 0; c < 4; ++c) {
                int4 hA = hs4[2*c], hB = hs4[2*c + 1];
                int4 cg  = wl[(2*c)      * 64 + lane];
                int4 cg2 = wl[(2*c + 1)  * 64 + lane];
                int4 co  = wl[(8 + 2*c)  * 64 + lane];
                int4 co2 = wl[(9 + 2*c)  * 64 + lane];
                int4 cu  = wl[(16 + 2*c) * 64 + lane];
                int4 cu2 = wl[(17 + 2*c) * 64 + lane];
                if (c == 2) { vh0 = wl[24 * 64 + lane]; vh1 = wl[25 * 64 + lane]; }

                ai = dot2(w1i[8*c+0], hA.x, ai); ai = dot2(w1i[8*c+1], hA.y, ai);
                ai = dot2(w1i[8*c+2], hA.z, ai); ai = dot2(w1i[8*c+3], hA.w, ai);
                ai = dot2(w1i[8*c+4], hB.x, ai); ai = dot2(w1i[8*c+5], hB.y, ai);
                ai = dot2(w1i[8*c+6], hB.z, ai); ai = dot2(w1i[8*c+7], hB.w, ai);

                af = dot2(w1f[8*c+0], hA.x, af); af = dot2(w1f[8*c+1], hA.y, af);
                af = dot2(w1f[8*c+2], hA.z, af); af = dot2(w1f[8*c+3], hA.w, af);
                af = dot2(w1f[8*c+4], hB.x, af); af = dot2(w1f[8*c+5], hB.y, af);
                af = dot2(w1f[8*c+6], hB.z, af); af = dot2(w1f[8*c+7], hB.w, af);

                ag = dot2(cg.x,  hA.x, ag); ag = dot2(cg.y,  hA.y, ag);
                ag = dot2(cg.z,  hA.z, ag); ag = dot2(cg.w,  hA.w, ag);
                ag = dot2(cg2.x, hB.x, ag); ag = dot2(cg2.y, hB.y, ag);
                ag = dot2(cg2.z, hB.z, ag); ag = dot2(cg2.w, hB.w, ag);

                ao = dot2(co.x,  hA.x, ao); ao = dot2(co.y,  hA.y, ao);
                ao = dot2(co.z,  hA.z, ao); ao = dot2(co.w,  hA.w, ao);
                ao = dot2(co2.x, hB.x, ao); ao = dot2(co2.y, hB.y, ao);
                ao = dot2(co2.z, hB.z, ao); ao = dot2(co2.w, hB.w, ao);

                a0  = dot2(cu.x,  hA.x, a0);  a1  = dot2(cu.y,  hA.y, a1);
                a2a = dot2(cu.z,  hA.z, a2a); a3  = dot2(cu.w,  hA.w, a3);
                a0  = dot2(cu2.x, hB.x, a0);  a1  = dot2(cu2.y, hB.y, a1);
                a2a = dot2(cu2.z, hB.z, a2a); a3  = dot2(cu2.w, hB.w, a3);
            }
        }

        // ===== Layer 1 finish, timestep p =====
        if (p < TSTEPS) {
            float gi = fsig(ai), gf = fsig(af), gg = ftanh(ag), go = fsig(ao);
            c1 = gf * c1 + gi * gg;
            float h1n = go * ftanh(c1);
            h1_lds[lane] = (_Float16)h1n;       // ds_write_b16; same-wave FIFO
        }

        // ===== Layer 2 finish, timestep p-1 (same wave, no sync) =====
        if (p >= 1) {
            const int4* hs = (const int4*)h2_lds;   // h2(p-2)
            int4 u0 = hs[0], u1 = hs[1];
            a0  = dot2(vh0.x, u0.x, a0);  a1  = dot2(vh0.y, u0.y, a1);
            a2a = dot2(vh0.z, u0.z, a2a); a3  = dot2(vh0.w, u0.w, a3);
            a0  = dot2(vh1.x, u1.x, a0);  a1  = dot2(vh1.y, u1.y, a1);
            a2a = dot2(vh1.z, u1.z, a2a); a3  = dot2(vh1.w, u1.w, a3);
            float av = act((a0 + a1) + (a2a + a3), k22);
            // gather the quad's 4 gates (i,f,g,o) via DPP broadcast
            float gi = dpp_bcast<0x00>(av);
            float gf = dpp_bcast<0x55>(av);
            float gg = dpp_bcast<0xAA>(av);
            float go = dpp_bcast<0xFF>(av);
            c2 = gf * c2 + gi * gg;
            float h2n = go * ftanh(c2);
            if (g2 == 0) {
                h2_lds[m] = (_Float16)h2n;
                ring[(p - 1) & 31][m] = h2n;
            }
        }
    }

    // ---- tail flush: timesteps 2032..2047 (same wave -> FIFO safe) ----
    {
        const int tt = 2032 + (lane >> 2), ch0 = (lane & 3) * 4;
        float4 v = *(const float4*)&ring[tt & 31][ch0];
        *(float4*)(outb + (size_t)tt * H2 + ch0) = v;
    }
}

extern "C" void kernel_launch(void* const* d_in, const int* in_sizes, int n_in,
                              void* d_out, int out_size, void* d_ws, size_t ws_size,
                              hipStream_t stream) {
    const float* x     = (const float*)d_in[0];
    const float* w_ih1 = (const float*)d_in[1];
    const float* w_hh1 = (const float*)d_in[2];
    const float* b_ih1 = (const float*)d_in[3];
    const float* b_hh1 = (const float*)d_in[4];
    const float* w_ih2 = (const float*)d_in[5];
    const float* w_hh2 = (const float*)d_in[6];
    const float* b_ih2 = (const float*)d_in[7];
    const float* b_hh2 = (const float*)d_in[8];
    float* out = (float*)d_out;

    lstm2_fused<<<NBATCH, 64, 0, stream>>>(x, w_ih1, w_hh1, b_ih1, b_hh1,
                                           w_ih2, w_hh2, b_ih2, b_hh2, out);
}